// Round 1
// baseline (485.826 us; speedup 1.0000x reference)
//
#include <hip/hip_runtime.h>
#include <math.h>

// Problem constants (from reference)
#define TT  4096
#define NBB 32
#define NUU 64
#define NHH 256
#define HH  128
#define NYY 64
// Chunked scan: C chunks of L steps
#define LCH 16
#define CCH (TT / LCH)   // 256

#define PI_HALF 1.5707963267948966f

// ---------------------------------------------------------------------------
// Kernel 1: per-chunk local end-state E_c (recurrence run from zero state).
// Grid: CCH blocks x 256 threads. Each block: all 32 batches, all 128 complex
// channels. Thread (bg,hg) owns 4 batches x 4 complex channels.
// ---------------------------------------------------------------------------
__global__ __launch_bounds__(256, 2) void k_chunk_end(
    const float* __restrict__ U, const float* __restrict__ B,
    const float* __restrict__ lre, const float* __restrict__ lim,
    float2* __restrict__ E)
{
    __shared__ float Bt[64 * 256];   // B transposed: Bt[u*256 + h] = B[h*64+u] (64 KB)
    __shared__ float Ub[64 * 33];    // U_t staged [u][b], +33 pad kills bank conflicts

    const int tid = threadIdx.x;
    const int c   = blockIdx.x;

    // Stage B transposed (reads uncoalesced but L2-cached; LDS writes conflict-free)
    for (int idx = tid; idx < 64 * 256; idx += 256) {
        int u = idx >> 8, h = idx & 255;
        Bt[idx] = B[h * 64 + u];
    }

    const int bg = tid >> 5;   // 0..7  -> batches bg*4 .. bg*4+3
    const int hg = tid & 31;   // 0..31 -> complex channels hg*4 .. hg*4+3

    float lr[4], li[4];
#pragma unroll
    for (int q = 0; q < 4; ++q) {
        int hc = hg * 4 + q;
        float r  = expf(-fabsf(lre[hc]));
        float th = PI_HALF * lim[hc];
        lr[q] = r * cosf(th);
        li[q] = r * sinf(th);
    }

    float zr[4][4] = {}, zi[4][4] = {};

    for (int k = 0; k < LCH; ++k) {
        int t = c * LCH + k;
        __syncthreads();   // prior step's Ub readers done
        // Stage U_t: 2048 floats, coalesced float4 reads
        const float4* Ug = (const float4*)(U + (size_t)t * (NBB * NUU));
#pragma unroll
        for (int n = 0; n < 2; ++n) {
            float4 v = Ug[tid * 2 + n];
            int base = tid * 8 + n * 4;
            int b = base >> 6;
            int u = base & 63;
            Ub[(u + 0) * 33 + b] = v.x;
            Ub[(u + 1) * 33 + b] = v.y;
            Ub[(u + 2) * 33 + b] = v.z;
            Ub[(u + 3) * 33 + b] = v.w;
        }
        __syncthreads();

        // Bu tile: 4b x 4hc (real+imag) = 32 accumulators
        float ar[4][4] = {}, ai[4][4] = {};
#pragma unroll 4
        for (int u = 0; u < 64; ++u) {
            float4 blo = *(const float4*)&Bt[u * 256 + hg * 4];
            float4 bhi = *(const float4*)&Bt[u * 256 + 128 + hg * 4];
            float uu[4];
#pragma unroll
            for (int j = 0; j < 4; ++j) uu[j] = Ub[u * 33 + bg * 4 + j];
#pragma unroll
            for (int j = 0; j < 4; ++j) {
                ar[j][0] += uu[j] * blo.x; ar[j][1] += uu[j] * blo.y;
                ar[j][2] += uu[j] * blo.z; ar[j][3] += uu[j] * blo.w;
                ai[j][0] += uu[j] * bhi.x; ai[j][1] += uu[j] * bhi.y;
                ai[j][2] += uu[j] * bhi.z; ai[j][3] += uu[j] * bhi.w;
            }
        }
        // state update
#pragma unroll
        for (int j = 0; j < 4; ++j)
#pragma unroll
            for (int q = 0; q < 4; ++q) {
                float nr = lr[q] * zr[j][q] - li[q] * zi[j][q] + ar[j][q];
                float ni = li[q] * zr[j][q] + lr[q] * zi[j][q] + ai[j][q];
                zr[j][q] = nr; zi[j][q] = ni;
            }
    }

    // Write E_c: per batch j, 4 consecutive float2 -> two coalesced float4 stores
#pragma unroll
    for (int j = 0; j < 4; ++j) {
        int b = bg * 4 + j;
        float4* dst = (float4*)&E[((size_t)c * NBB + b) * HH + hg * 4];
        dst[0] = make_float4(zr[j][0], zi[j][0], zr[j][1], zi[j][1]);
        dst[1] = make_float4(zr[j][2], zi[j][2], zr[j][3], zi[j][3]);
    }
}

// ---------------------------------------------------------------------------
// Kernel 2: x0 = y0 @ W_y2x^T + b_y2x, then carry scan across chunks.
// 4096 independent (b,hc) chains. Grid: 64 blocks x 64 threads.
// Carry[c] = state BEFORE chunk c (z_{cL-1}), Carry[0] = x0.
// ---------------------------------------------------------------------------
__global__ __launch_bounds__(64) void k_carry(
    const float* __restrict__ y0, const float* __restrict__ W_y2x,
    const float* __restrict__ b_y2x,
    const float* __restrict__ lre, const float* __restrict__ lim,
    const float2* __restrict__ E, float2* __restrict__ Carry)
{
    int g  = blockIdx.x * 64 + threadIdx.x;   // 0..4095
    int b  = g >> 7;
    int hc = g & 127;

    // x0 for this (b, hc)
    float xr = b_y2x[hc], xi = b_y2x[hc + HH];
    for (int y = 0; y < NYY; ++y) {
        float yv = y0[b * NYY + y];
        xr += yv * W_y2x[hc * NYY + y];
        xi += yv * W_y2x[(hc + HH) * NYY + y];
    }

    // lambda^L via 4 complex squarings of the fp32 lambda (L = 16)
    float r  = expf(-fabsf(lre[hc]));
    float th = PI_HALF * lim[hc];
    float plr = r * cosf(th), pli = r * sinf(th);
#pragma unroll
    for (int s = 0; s < 4; ++s) {
        float nr = plr * plr - pli * pli;
        float ni = 2.0f * plr * pli;
        plr = nr; pli = ni;
    }

    float cr = xr, ci = xi;
#pragma unroll 16
    for (int c = 0; c < CCH; ++c) {
        size_t idx = ((size_t)c * NBB + b) * HH + hc;
        Carry[idx] = make_float2(cr, ci);
        float2 e = E[idx];
        float nr = plr * cr - pli * ci + e.x;
        float ni = pli * cr + plr * ci + e.y;
        cr = nr; ci = ni;
    }
}

// ---------------------------------------------------------------------------
// Kernel 3: main pass. Per chunk: recompute Bu, run recurrence seeded with the
// true carry, and fuse Y = [Re z; Im z] @ W_x2y^T + b_x2y each step.
// W_x2y cached in registers (thread (yy,kg) holds W[yy][kg*64..kg*64+63]);
// z broadcast from LDS; split-K partials reduced through LDS.
// ---------------------------------------------------------------------------
__global__ __launch_bounds__(256, 1) void k_main(
    const float* __restrict__ U, const float* __restrict__ B,
    const float* __restrict__ lre, const float* __restrict__ lim,
    const float* __restrict__ W_x2y, const float* __restrict__ b_x2y,
    const float2* __restrict__ Carry, float* __restrict__ Y)
{
    __shared__ float Bt[64 * 256];        // 64 KB
    __shared__ float Ub[64 * 33];         // 8.25 KB
    __shared__ float Zl[NBB * NHH];       // 32 KB: [b][kk], kk<128 = Re, >=128 = Im
    __shared__ float Sc[4 * NBB * NYY];   // 32 KB: split-K partials [kg][b][y]

    const int tid = threadIdx.x;
    const int c   = blockIdx.x;

    for (int idx = tid; idx < 64 * 256; idx += 256) {
        int u = idx >> 8, h = idx & 255;
        Bt[idx] = B[h * 64 + u];
    }

    const int bg = tid >> 5, hg = tid & 31;   // scan mapping
    const int yy = tid & 63, kg = tid >> 6;   // output-GEMM mapping

    // W registers: W_x2y[yy][kg*64 + m], m = 0..63
    float Wreg[64];
    {
        const float4* Wg = (const float4*)(W_x2y + yy * NHH + kg * 64);
#pragma unroll
        for (int m4 = 0; m4 < 16; ++m4) {
            float4 w = Wg[m4];
            Wreg[m4 * 4 + 0] = w.x; Wreg[m4 * 4 + 1] = w.y;
            Wreg[m4 * 4 + 2] = w.z; Wreg[m4 * 4 + 3] = w.w;
        }
    }

    float lr[4], li[4];
#pragma unroll
    for (int q = 0; q < 4; ++q) {
        int hc = hg * 4 + q;
        float r  = expf(-fabsf(lre[hc]));
        float th = PI_HALF * lim[hc];
        lr[q] = r * cosf(th);
        li[q] = r * sinf(th);
    }

    // Seed state from Carry
    float zr[4][4], zi[4][4];
#pragma unroll
    for (int j = 0; j < 4; ++j) {
        const float4* src = (const float4*)&Carry[((size_t)c * NBB + bg * 4 + j) * HH + hg * 4];
        float4 v0 = src[0], v1 = src[1];
        zr[j][0] = v0.x; zi[j][0] = v0.y; zr[j][1] = v0.z; zi[j][1] = v0.w;
        zr[j][2] = v1.x; zi[j][2] = v1.y; zr[j][3] = v1.z; zi[j][3] = v1.w;
    }

    for (int k = 0; k < LCH; ++k) {
        int t = c * LCH + k;
        __syncthreads();   // prior step's Ub/Zl/Sc readers done
        const float4* Ug = (const float4*)(U + (size_t)t * (NBB * NUU));
#pragma unroll
        for (int n = 0; n < 2; ++n) {
            float4 v = Ug[tid * 2 + n];
            int base = tid * 8 + n * 4;
            int b = base >> 6;
            int u = base & 63;
            Ub[(u + 0) * 33 + b] = v.x;
            Ub[(u + 1) * 33 + b] = v.y;
            Ub[(u + 2) * 33 + b] = v.z;
            Ub[(u + 3) * 33 + b] = v.w;
        }
        __syncthreads();

        float ar[4][4] = {}, ai[4][4] = {};
#pragma unroll 4
        for (int u = 0; u < 64; ++u) {
            float4 blo = *(const float4*)&Bt[u * 256 + hg * 4];
            float4 bhi = *(const float4*)&Bt[u * 256 + 128 + hg * 4];
            float uu[4];
#pragma unroll
            for (int j = 0; j < 4; ++j) uu[j] = Ub[u * 33 + bg * 4 + j];
#pragma unroll
            for (int j = 0; j < 4; ++j) {
                ar[j][0] += uu[j] * blo.x; ar[j][1] += uu[j] * blo.y;
                ar[j][2] += uu[j] * blo.z; ar[j][3] += uu[j] * blo.w;
                ai[j][0] += uu[j] * bhi.x; ai[j][1] += uu[j] * bhi.y;
                ai[j][2] += uu[j] * bhi.z; ai[j][3] += uu[j] * bhi.w;
            }
        }
#pragma unroll
        for (int j = 0; j < 4; ++j)
#pragma unroll
            for (int q = 0; q < 4; ++q) {
                float nr = lr[q] * zr[j][q] - li[q] * zi[j][q] + ar[j][q];
                float ni = li[q] * zr[j][q] + lr[q] * zi[j][q] + ai[j][q];
                zr[j][q] = nr; zi[j][q] = ni;
            }

        // Publish z to LDS (conflict-free float4 stores)
#pragma unroll
        for (int j = 0; j < 4; ++j) {
            int b = bg * 4 + j;
            *(float4*)&Zl[b * NHH + hg * 4]      = make_float4(zr[j][0], zr[j][1], zr[j][2], zr[j][3]);
            *(float4*)&Zl[b * NHH + HH + hg * 4] = make_float4(zi[j][0], zi[j][1], zi[j][2], zi[j][3]);
        }
        __syncthreads();

        // Output GEMM partials: thread (yy,kg) does all 32 b over its K-slice.
        // z reads are wave-uniform (broadcast); 4 accumulators break dep chains.
        for (int b = 0; b < NBB; ++b) {
            const float4* zp = (const float4*)&Zl[b * NHH + kg * 64];
            float a0 = 0.f, a1 = 0.f, a2 = 0.f, a3 = 0.f;
#pragma unroll
            for (int m4 = 0; m4 < 16; m4 += 4) {
                float4 z0 = zp[m4 + 0], z1 = zp[m4 + 1], z2 = zp[m4 + 2], z3 = zp[m4 + 3];
                a0 += z0.x * Wreg[(m4 + 0) * 4 + 0] + z0.y * Wreg[(m4 + 0) * 4 + 1]
                    + z0.z * Wreg[(m4 + 0) * 4 + 2] + z0.w * Wreg[(m4 + 0) * 4 + 3];
                a1 += z1.x * Wreg[(m4 + 1) * 4 + 0] + z1.y * Wreg[(m4 + 1) * 4 + 1]
                    + z1.z * Wreg[(m4 + 1) * 4 + 2] + z1.w * Wreg[(m4 + 1) * 4 + 3];
                a2 += z2.x * Wreg[(m4 + 2) * 4 + 0] + z2.y * Wreg[(m4 + 2) * 4 + 1]
                    + z2.z * Wreg[(m4 + 2) * 4 + 2] + z2.w * Wreg[(m4 + 2) * 4 + 3];
                a3 += z3.x * Wreg[(m4 + 3) * 4 + 0] + z3.y * Wreg[(m4 + 3) * 4 + 1]
                    + z3.z * Wreg[(m4 + 3) * 4 + 2] + z3.w * Wreg[(m4 + 3) * 4 + 3];
            }
            Sc[(kg * NBB + b) * NYY + yy] = (a0 + a1) + (a2 + a3);
        }
        __syncthreads();

        // Reduce split-K partials + bias, write Y (coalesced)
#pragma unroll
        for (int i = 0; i < 8; ++i) {
            int o = tid + 256 * i;            // 0..2047
            int b = o >> 6, y = o & 63;
            float s = Sc[(0 * NBB + b) * NYY + y] + Sc[(1 * NBB + b) * NYY + y]
                    + Sc[(2 * NBB + b) * NYY + y] + Sc[(3 * NBB + b) * NYY + y]
                    + b_x2y[y];
            Y[(size_t)t * (NBB * NYY) + o] = s;
        }
    }
}

// ---------------------------------------------------------------------------
extern "C" void kernel_launch(void* const* d_in, const int* in_sizes, int n_in,
                              void* d_out, int out_size, void* d_ws, size_t ws_size,
                              hipStream_t stream) {
    const float* y0    = (const float*)d_in[0];
    const float* U     = (const float*)d_in[1];
    const float* lre   = (const float*)d_in[2];
    const float* lim   = (const float*)d_in[3];
    const float* B     = (const float*)d_in[4];
    const float* W_y2x = (const float*)d_in[5];
    const float* b_y2x = (const float*)d_in[6];
    const float* W_x2y = (const float*)d_in[7];
    const float* b_x2y = (const float*)d_in[8];
    float* Y = (float*)d_out;

    // Workspace: E (C*NB*H float2 = 8 MB) then Carry (8 MB)
    float2* E     = (float2*)d_ws;
    float2* Carry = E + (size_t)CCH * NBB * HH;

    k_chunk_end<<<dim3(CCH), dim3(256), 0, stream>>>(U, B, lre, lim, E);
    k_carry<<<dim3(64), dim3(64), 0, stream>>>(y0, W_y2x, b_y2x, lre, lim, E, Carry);
    k_main<<<dim3(CCH), dim3(256), 0, stream>>>(U, B, lre, lim, W_x2y, b_x2y, Carry, Y);
}

// Round 2
// 165.763 us; speedup vs baseline: 2.9309x; 2.9309x over previous
//
#include <hip/hip_runtime.h>
#include <math.h>

// Problem constants
#define TT  4096
#define NBB 32
#define NUU 64
#define NHH 256
#define HH  128
#define NYY 64
#define LCH 16
#define CCH (TT / LCH)   // 256
#define LSUB 4
#define NSUB (LCH / LSUB)

#define PI_HALF 1.5707963267948966f

typedef float    f32x16 __attribute__((ext_vector_type(16)));
typedef __bf16   bf16x8 __attribute__((ext_vector_type(8)));
typedef unsigned int uint4v __attribute__((ext_vector_type(4)));

__device__ inline unsigned short f2bf(float f) {
    unsigned int u = __float_as_uint(f);
    return (unsigned short)((u + 0x7fffu + ((u >> 16) & 1u)) >> 16);
}
__device__ inline unsigned int pk(float a, float b) {
    return (unsigned int)f2bf(a) | ((unsigned int)f2bf(b) << 16);
}
__device__ inline bf16x8 ldsfrag(const unsigned short* p) {
    return __builtin_bit_cast(bf16x8, *(const uint4v*)p);
}
// C/D tile row for reg r: row = (r&3) + 8*(r>>2) + 4*(lane>>5)
__device__ inline int crow(int r, int lane) { return (r & 3) + 8 * (r >> 2) + 4 * (lane >> 5); }

// ---------------------------------------------------------------------------
// Pass 1: per-chunk local end state E_c via MFMA Bu + in-register scan.
// Column layout is PERMUTED: n=2j -> real channel j, n=2j+1 -> imag channel j.
// ---------------------------------------------------------------------------
__global__ __launch_bounds__(256, 1) void k_pass1(
    const float* __restrict__ U, const float* __restrict__ B,
    const float* __restrict__ lre, const float* __restrict__ lim,
    float* __restrict__ E)
{
    __shared__ __align__(16) unsigned short sB[256 * 72];  // [n][u], stride 72
    __shared__ __align__(16) unsigned short sU[128 * 72];  // [m=(k,b)][u]

    const int tid  = threadIdx.x;
    const int w    = tid >> 6;
    const int lane = tid & 63;
    const int c    = blockIdx.x;

    // Stage B (permuted columns) as bf16
    for (int i = tid; i < 2048; i += 256) {
        int n = i >> 3, seg = i & 7;
        int h = (n >> 1) + (n & 1) * HH;
        const float4* src = (const float4*)(B + (size_t)h * 64 + seg * 8);
        float4 f0 = src[0], f1 = src[1];
        uint4v p;
        p.x = pk(f0.x, f0.y); p.y = pk(f0.z, f0.w);
        p.z = pk(f1.x, f1.y); p.w = pk(f1.z, f1.w);
        *(uint4v*)&sB[n * 72 + seg * 8] = p;
    }

    // Per-lane lambda (2 n-tiles per wave)
    float lr[2], li_s[2];
#pragma unroll
    for (int nt = 0; nt < 2; ++nt) {
        int j = (w * 64 + nt * 32 + (lane & 31)) >> 1;
        float r_ = expf(-fabsf(lre[j]));
        float th = PI_HALF * lim[j];
        lr[nt] = r_ * cosf(th);
        float li = r_ * sinf(th);
        li_s[nt] = (lane & 1) ? li : -li;
    }
    __syncthreads();

    // Hoist B fragments (same across sub-chunks)
    bf16x8 bfrag[2][4];
#pragma unroll
    for (int nt = 0; nt < 2; ++nt)
#pragma unroll
        for (int kk = 0; kk < 4; ++kk)
            bfrag[nt][kk] = ldsfrag(&sB[(w * 64 + nt * 32 + (lane & 31)) * 72 + kk * 16 + (lane >> 5) * 8]);

    float z[2][16];
#pragma unroll
    for (int nt = 0; nt < 2; ++nt)
#pragma unroll
        for (int r = 0; r < 16; ++r) z[nt][r] = 0.f;

    for (int sub = 0; sub < NSUB; ++sub) {
        // Stage U sub-chunk (128 rows x 64 u) as bf16
        for (int i = tid; i < 1024; i += 256) {
            int row = i >> 3, seg = i & 7;
            int t = c * LCH + sub * LSUB + (row >> 5);
            int b = row & 31;
            const float4* src = (const float4*)(U + ((size_t)t * NBB + b) * NUU + seg * 8);
            float4 f0 = src[0], f1 = src[1];
            uint4v p;
            p.x = pk(f0.x, f0.y); p.y = pk(f0.z, f0.w);
            p.z = pk(f1.x, f1.y); p.w = pk(f1.z, f1.w);
            *(uint4v*)&sU[row * 72 + seg * 8] = p;
        }
        __syncthreads();

        // Bu GEMM: M=128 (4 tiles), N=64 per wave (2 tiles), K=64
        f32x16 acc[4][2];
#pragma unroll
        for (int mt = 0; mt < 4; ++mt)
#pragma unroll
            for (int nt = 0; nt < 2; ++nt)
#pragma unroll
                for (int r = 0; r < 16; ++r) acc[mt][nt][r] = 0.f;

#pragma unroll
        for (int kk = 0; kk < 4; ++kk) {
            bf16x8 afr[4];
#pragma unroll
            for (int mt = 0; mt < 4; ++mt)
                afr[mt] = ldsfrag(&sU[(mt * 32 + (lane & 31)) * 72 + kk * 16 + (lane >> 5) * 8]);
#pragma unroll
            for (int mt = 0; mt < 4; ++mt)
#pragma unroll
                for (int nt = 0; nt < 2; ++nt)
                    acc[mt][nt] = __builtin_amdgcn_mfma_f32_32x32x16_bf16(afr[mt], bfrag[nt][kk], acc[mt][nt], 0, 0, 0);
        }

        // In-register scan over the 4 time steps (complex pair = lane^1)
#pragma unroll
        for (int mt = 0; mt < LSUB; ++mt) {
#pragma unroll
            for (int nt = 0; nt < 2; ++nt) {
                float p[16];
#pragma unroll
                for (int r = 0; r < 16; ++r) p[r] = __shfl_xor(z[nt][r], 1, 64);
#pragma unroll
                for (int r = 0; r < 16; ++r) {
                    float t0 = fmaf(lr[nt], z[nt][r], acc[mt][nt][r]);
                    z[nt][r] = fmaf(li_s[nt], p[r], t0);
                }
            }
        }
        __syncthreads();   // before next sU overwrite
    }

    // Write E (fp32, permuted layout: pairs adjacent)
#pragma unroll
    for (int nt = 0; nt < 2; ++nt)
#pragma unroll
        for (int r = 0; r < 16; ++r) {
            int b = crow(r, lane);
            int n = w * 64 + nt * 32 + (lane & 31);
            E[((size_t)c * NBB + b) * NHH + n] = z[nt][r];
        }
}

// ---------------------------------------------------------------------------
// Carry: x0 = y0 @ W_y2x^T + b_y2x, then serial carry over 256 chunks.
// E/Carry float2 at [(c*32+b)*128 + j] = (re_j, im_j)  (matches permuted layout)
// ---------------------------------------------------------------------------
__global__ __launch_bounds__(64) void k_carry(
    const float* __restrict__ y0, const float* __restrict__ W_y2x,
    const float* __restrict__ b_y2x,
    const float* __restrict__ lre, const float* __restrict__ lim,
    const float2* __restrict__ E, float2* __restrict__ Carry)
{
    int g  = blockIdx.x * 64 + threadIdx.x;   // 0..4095
    int b  = g >> 7;
    int hc = g & 127;

    float xr = b_y2x[hc], xi = b_y2x[hc + HH];
    for (int y = 0; y < NYY; ++y) {
        float yv = y0[b * NYY + y];
        xr += yv * W_y2x[hc * NYY + y];
        xi += yv * W_y2x[(hc + HH) * NYY + y];
    }

    float r  = expf(-fabsf(lre[hc]));
    float th = PI_HALF * lim[hc];
    float plr = r * cosf(th), pli = r * sinf(th);
#pragma unroll
    for (int s = 0; s < 4; ++s) {
        float nr = plr * plr - pli * pli;
        float ni = 2.0f * plr * pli;
        plr = nr; pli = ni;
    }

    float cr = xr, ci = xi;
#pragma unroll 16
    for (int c = 0; c < CCH; ++c) {
        size_t idx = ((size_t)c * NBB + b) * HH + hc;
        Carry[idx] = make_float2(cr, ci);
        float2 e = E[idx];
        float nr = plr * cr - pli * ci + e.x;
        float ni = pli * cr + plr * ci + e.y;
        cr = nr; ci = ni;
    }
}

// ---------------------------------------------------------------------------
// Pass 2: seeded scan + fused output GEMM (all MFMA).
// ---------------------------------------------------------------------------
__global__ __launch_bounds__(256, 1) void k_pass2(
    const float* __restrict__ U, const float* __restrict__ B,
    const float* __restrict__ lre, const float* __restrict__ lim,
    const float* __restrict__ W_x2y, const float* __restrict__ b_x2y,
    const float* __restrict__ Carry, float* __restrict__ Y)
{
    __shared__ __align__(16) unsigned short sB[256 * 72];   // 36.0 KB
    __shared__ __align__(16) unsigned short sU[128 * 72];   // 18.0 KB
    __shared__ __align__(16) unsigned short sX[128 * 264];  // 66.0 KB
    __shared__ __align__(16) unsigned short sW[64 * 264];   // 33.0 KB

    const int tid  = threadIdx.x;
    const int w    = tid >> 6;
    const int lane = tid & 63;
    const int c    = blockIdx.x;

    // Stage B (permuted cols)
    for (int i = tid; i < 2048; i += 256) {
        int n = i >> 3, seg = i & 7;
        int h = (n >> 1) + (n & 1) * HH;
        const float4* src = (const float4*)(B + (size_t)h * 64 + seg * 8);
        float4 f0 = src[0], f1 = src[1];
        uint4v p;
        p.x = pk(f0.x, f0.y); p.y = pk(f0.z, f0.w);
        p.z = pk(f1.x, f1.y); p.w = pk(f1.z, f1.w);
        *(uint4v*)&sB[n * 72 + seg * 8] = p;
    }
    // Stage W_x2y with K permuted to match X columns: sW[y][k], k=2j->col j, 2j+1->col j+128
    for (int i = tid; i < 2048; i += 256) {
        int y = i >> 5, seg = i & 31;          // seg: 8 k-values = 4 complex pairs
        const float4* plo = (const float4*)(W_x2y + (size_t)y * NHH + seg * 4);
        const float4* phi = (const float4*)(W_x2y + (size_t)y * NHH + HH + seg * 4);
        float4 lo = plo[0], hi = phi[0];
        uint4v p;
        p.x = pk(lo.x, hi.x); p.y = pk(lo.y, hi.y);
        p.z = pk(lo.z, hi.z); p.w = pk(lo.w, hi.w);
        *(uint4v*)&sW[y * 264 + seg * 8] = p;
    }

    float lr[2], li_s[2];
#pragma unroll
    for (int nt = 0; nt < 2; ++nt) {
        int j = (w * 64 + nt * 32 + (lane & 31)) >> 1;
        float r_ = expf(-fabsf(lre[j]));
        float th = PI_HALF * lim[j];
        lr[nt] = r_ * cosf(th);
        float li = r_ * sinf(th);
        li_s[nt] = (lane & 1) ? li : -li;
    }
    float ybias[2];
#pragma unroll
    for (int nt2 = 0; nt2 < 2; ++nt2) ybias[nt2] = b_x2y[nt2 * 32 + (lane & 31)];

    // Seed z from Carry
    float z[2][16];
#pragma unroll
    for (int nt = 0; nt < 2; ++nt)
#pragma unroll
        for (int r = 0; r < 16; ++r) {
            int b = crow(r, lane);
            int n = w * 64 + nt * 32 + (lane & 31);
            z[nt][r] = Carry[((size_t)c * NBB + b) * NHH + n];
        }

    __syncthreads();

    bf16x8 bfrag[2][4];
#pragma unroll
    for (int nt = 0; nt < 2; ++nt)
#pragma unroll
        for (int kk = 0; kk < 4; ++kk)
            bfrag[nt][kk] = ldsfrag(&sB[(w * 64 + nt * 32 + (lane & 31)) * 72 + kk * 16 + (lane >> 5) * 8]);

    for (int sub = 0; sub < NSUB; ++sub) {
        // Stage U sub-chunk
        for (int i = tid; i < 1024; i += 256) {
            int row = i >> 3, seg = i & 7;
            int t = c * LCH + sub * LSUB + (row >> 5);
            int b = row & 31;
            const float4* src = (const float4*)(U + ((size_t)t * NBB + b) * NUU + seg * 8);
            float4 f0 = src[0], f1 = src[1];
            uint4v p;
            p.x = pk(f0.x, f0.y); p.y = pk(f0.z, f0.w);
            p.z = pk(f1.x, f1.y); p.w = pk(f1.z, f1.w);
            *(uint4v*)&sU[row * 72 + seg * 8] = p;
        }
        __syncthreads();

        // Bu GEMM into registers
        f32x16 acc[4][2];
#pragma unroll
        for (int mt = 0; mt < 4; ++mt)
#pragma unroll
            for (int nt = 0; nt < 2; ++nt)
#pragma unroll
                for (int r = 0; r < 16; ++r) acc[mt][nt][r] = 0.f;

#pragma unroll
        for (int kk = 0; kk < 4; ++kk) {
            bf16x8 afr[4];
#pragma unroll
            for (int mt = 0; mt < 4; ++mt)
                afr[mt] = ldsfrag(&sU[(mt * 32 + (lane & 31)) * 72 + kk * 16 + (lane >> 5) * 8]);
#pragma unroll
            for (int mt = 0; mt < 4; ++mt)
#pragma unroll
                for (int nt = 0; nt < 2; ++nt)
                    acc[mt][nt] = __builtin_amdgcn_mfma_f32_32x32x16_bf16(afr[mt], bfrag[nt][kk], acc[mt][nt], 0, 0, 0);
        }

        // Scan + dump X (bf16) to LDS
#pragma unroll
        for (int mt = 0; mt < LSUB; ++mt) {
#pragma unroll
            for (int nt = 0; nt < 2; ++nt) {
                float p[16];
#pragma unroll
                for (int r = 0; r < 16; ++r) p[r] = __shfl_xor(z[nt][r], 1, 64);
#pragma unroll
                for (int r = 0; r < 16; ++r) {
                    float t0 = fmaf(lr[nt], z[nt][r], acc[mt][nt][r]);
                    z[nt][r] = fmaf(li_s[nt], p[r], t0);
                    int lrow = crow(r, lane);
                    sX[(mt * 32 + lrow) * 264 + w * 64 + nt * 32 + (lane & 31)] = f2bf(z[nt][r]);
                }
            }
        }
        __syncthreads();

        // Output GEMM: wave w handles time-row tile w (M=32), K=256, N=64
        f32x16 yacc[2];
#pragma unroll
        for (int nt2 = 0; nt2 < 2; ++nt2)
#pragma unroll
            for (int r = 0; r < 16; ++r) yacc[nt2][r] = 0.f;

#pragma unroll
        for (int kk = 0; kk < 16; ++kk) {
            bf16x8 xa = ldsfrag(&sX[(w * 32 + (lane & 31)) * 264 + kk * 16 + (lane >> 5) * 8]);
#pragma unroll
            for (int nt2 = 0; nt2 < 2; ++nt2) {
                bf16x8 wb = ldsfrag(&sW[(nt2 * 32 + (lane & 31)) * 264 + kk * 16 + (lane >> 5) * 8]);
                yacc[nt2] = __builtin_amdgcn_mfma_f32_32x32x16_bf16(xa, wb, yacc[nt2], 0, 0, 0);
            }
        }

        // Epilogue: Y[t][b][y] = yacc + bias, t = c*16 + sub*4 + w
        int t = c * LCH + sub * LSUB + w;
#pragma unroll
        for (int nt2 = 0; nt2 < 2; ++nt2)
#pragma unroll
            for (int r = 0; r < 16; ++r) {
                int b = crow(r, lane);
                int y = nt2 * 32 + (lane & 31);
                Y[((size_t)t * NBB + b) * NYY + y] = yacc[nt2][r] + ybias[nt2];
            }
        // NOTE: next iteration's sU staging doesn't touch sX/sW; the
        // post-staging __syncthreads() fences this sub's sX readers before
        // the next scan overwrites sX.
    }
}

// ---------------------------------------------------------------------------
extern "C" void kernel_launch(void* const* d_in, const int* in_sizes, int n_in,
                              void* d_out, int out_size, void* d_ws, size_t ws_size,
                              hipStream_t stream) {
    const float* y0    = (const float*)d_in[0];
    const float* U     = (const float*)d_in[1];
    const float* lre   = (const float*)d_in[2];
    const float* lim   = (const float*)d_in[3];
    const float* B     = (const float*)d_in[4];
    const float* W_y2x = (const float*)d_in[5];
    const float* b_y2x = (const float*)d_in[6];
    const float* W_x2y = (const float*)d_in[7];
    const float* b_x2y = (const float*)d_in[8];
    float* Y = (float*)d_out;

    float* E     = (float*)d_ws;                       // 8 MB
    float* Carry = E + (size_t)CCH * NBB * NHH;        // 8 MB

    k_pass1<<<dim3(CCH), dim3(256), 0, stream>>>(U, B, lre, lim, E);
    k_carry<<<dim3(64), dim3(64), 0, stream>>>(y0, W_y2x, b_y2x, lre, lim,
                                               (const float2*)E, (float2*)Carry);
    k_pass2<<<dim3(CCH), dim3(256), 0, stream>>>(U, B, lre, lim, W_x2y, b_x2y, Carry, Y);
}

// Round 3
// 142.731 us; speedup vs baseline: 3.4038x; 1.1614x over previous
//
#include <hip/hip_runtime.h>
#include <math.h>

// Problem constants
#define TT   4096
#define NBB  32
#define NUU  64
#define NHH  256
#define HH   128
#define NYY  64
// Chunking: 512 chunks of 8 steps; carry hierarchy: 16 supers x 32 chunks
#define LCH  8
#define CCH  512
#define SEGN 16
#define CPS  32

#define PI_HALF 1.5707963267948966f

typedef float  f32x16 __attribute__((ext_vector_type(16)));
typedef __bf16 bf16x8 __attribute__((ext_vector_type(8)));
typedef __bf16 bf16x2 __attribute__((ext_vector_type(2)));
typedef unsigned int uint4v __attribute__((ext_vector_type(4)));

// MFMA 32x32 C/D layout: row = (r&3) + 8*(r>>2) + 4*(lane>>5), col = lane&31
__device__ inline int crow(int r, int lane) { return (r & 3) + 8 * (r >> 2) + 4 * (lane >> 5); }
__device__ inline bf16x8 ldfrag(const unsigned short* p) {
    return __builtin_bit_cast(bf16x8, *(const uint4v*)p);
}

// ---------------------------------------------------------------------------
// Prep: x0 pairs, bf16 B (plain), bf16 W_x2y with interleaved K permute:
// Wp[y][2j] = W[y][j], Wp[y][2j+1] = W[y][j+128].
// ---------------------------------------------------------------------------
__global__ __launch_bounds__(256) void k_prep(
    const float* __restrict__ B, const float* __restrict__ W,
    const float* __restrict__ y0, const float* __restrict__ Wy2x,
    const float* __restrict__ by2x,
    unsigned short* __restrict__ Bp, unsigned short* __restrict__ Wp,
    float2* __restrict__ x0p)
{
    int bx = blockIdx.x, tid = threadIdx.x;
    if (bx < 32) {
        if (tid < HH) {
            int b = bx, ch = tid;
            float xr = by2x[ch], xi = by2x[ch + HH];
            for (int y = 0; y < NYY; ++y) {
                float v = y0[b * NYY + y];
                xr += v * Wy2x[ch * NYY + y];
                xi += v * Wy2x[(ch + HH) * NYY + y];
            }
            x0p[b * HH + ch] = make_float2(xr, xi);
        }
    } else {
        int i = (bx - 32) * 256 + tid;            // 0..16383
        Bp[i] = __builtin_bit_cast(unsigned short, (__bf16)B[i]);
        int y = i >> 8, kidx = i & 255;
        Wp[i] = __builtin_bit_cast(unsigned short, (__bf16)W[y * NHH + (kidx & 1) * HH + (kidx >> 1)]);
    }
}

// ---------------------------------------------------------------------------
// Pass 1: per-chunk (L=8) local end state E_c. Wave w owns channel-pair tiles
// (re rows j=w*32.., im rows 128+j) -> lane holds (zr,zi) of one channel: the
// complex scan is 4 in-lane FMAs, no shuffles.
// ---------------------------------------------------------------------------
__global__ __launch_bounds__(256, 2) void k_pass1(
    const float* __restrict__ U, const unsigned short* __restrict__ Bp,
    const float* __restrict__ lre, const float* __restrict__ lim,
    float2* __restrict__ E)
{
    __shared__ __align__(16) unsigned short sU[64 * 72];   // 9 KB

    const int tid = threadIdx.x, w = tid >> 6, lane = tid & 63;
    const int l31 = lane & 31, kh = lane >> 5;
    const int c = blockIdx.x;
    const int ch = w * 32 + l31;

    float rr = expf(-fabsf(lre[ch])), th = PI_HALF * lim[ch];
    float lr = rr * cosf(th), li = rr * sinf(th);

    // Hoist B fragments: nt=0 -> re rows (h=ch), nt=1 -> im rows (h=128+ch)
    bf16x8 bf[2][4];
#pragma unroll
    for (int nt = 0; nt < 2; ++nt)
#pragma unroll
        for (int kk = 0; kk < 4; ++kk)
            bf[nt][kk] = ldfrag(&Bp[(size_t)(nt * HH + ch) * NUU + kk * 16 + kh * 8]);

    float zr[16], zi[16];
#pragma unroll
    for (int r = 0; r < 16; ++r) { zr[r] = 0.f; zi[r] = 0.f; }

    for (int sub = 0; sub < 4; ++sub) {
        {   // stage U (2 t x 32 b x 64 u) as bf16, thread -> 16 floats
            int row = tid >> 2, us = (tid & 3) * 16;
            int t = c * LCH + sub * 2 + (row >> 5), b = row & 31;
            const float4* s = (const float4*)(U + ((size_t)t * NBB + b) * NUU + us);
            float4 f0 = s[0], f1 = s[1], f2 = s[2], f3 = s[3];
            bf16x8 p0, p1;
            p0[0]=(__bf16)f0.x; p0[1]=(__bf16)f0.y; p0[2]=(__bf16)f0.z; p0[3]=(__bf16)f0.w;
            p0[4]=(__bf16)f1.x; p0[5]=(__bf16)f1.y; p0[6]=(__bf16)f1.z; p0[7]=(__bf16)f1.w;
            p1[0]=(__bf16)f2.x; p1[1]=(__bf16)f2.y; p1[2]=(__bf16)f2.z; p1[3]=(__bf16)f2.w;
            p1[4]=(__bf16)f3.x; p1[5]=(__bf16)f3.y; p1[6]=(__bf16)f3.z; p1[7]=(__bf16)f3.w;
            *(bf16x8*)&sU[row * 72 + us]     = p0;
            *(bf16x8*)&sU[row * 72 + us + 8] = p1;
        }
        __syncthreads();

        f32x16 acc[2][2];
#pragma unroll
        for (int mt = 0; mt < 2; ++mt)
#pragma unroll
            for (int nt = 0; nt < 2; ++nt)
#pragma unroll
                for (int r = 0; r < 16; ++r) acc[mt][nt][r] = 0.f;

#pragma unroll
        for (int kk = 0; kk < 4; ++kk) {
            bf16x8 a0 = ldfrag(&sU[(l31)      * 72 + kk * 16 + kh * 8]);
            bf16x8 a1 = ldfrag(&sU[(32 + l31) * 72 + kk * 16 + kh * 8]);
            acc[0][0] = __builtin_amdgcn_mfma_f32_32x32x16_bf16(a0, bf[0][kk], acc[0][0], 0, 0, 0);
            acc[0][1] = __builtin_amdgcn_mfma_f32_32x32x16_bf16(a0, bf[1][kk], acc[0][1], 0, 0, 0);
            acc[1][0] = __builtin_amdgcn_mfma_f32_32x32x16_bf16(a1, bf[0][kk], acc[1][0], 0, 0, 0);
            acc[1][1] = __builtin_amdgcn_mfma_f32_32x32x16_bf16(a1, bf[1][kk], acc[1][1], 0, 0, 0);
        }

#pragma unroll
        for (int mt = 0; mt < 2; ++mt)
#pragma unroll
            for (int r = 0; r < 16; ++r) {
                float t0 = fmaf(lr, zr[r], acc[mt][0][r]); t0 = fmaf(-li, zi[r], t0);
                float t1 = fmaf(li, zr[r], acc[mt][1][r]); t1 = fmaf(lr, zi[r], t1);
                zr[r] = t0; zi[r] = t1;
            }
        __syncthreads();
    }

#pragma unroll
    for (int r = 0; r < 16; ++r)
        E[(size_t)c * 4096 + crow(r, lane) * HH + ch] = make_float2(zr[r], zi[r]);
}

// ---------------------------------------------------------------------------
// Carry hierarchy. chain = b*128 + ch (4096 chains).
// ---------------------------------------------------------------------------
__global__ __launch_bounds__(256) void k_cseg(
    const float* __restrict__ lre, const float* __restrict__ lim,
    const float2* __restrict__ E, float2* __restrict__ Esup)
{
    int g = blockIdx.x * 256 + threadIdx.x;
    int chain = g & 4095, seg = g >> 12, ch = chain & 127;
    float rr = expf(-fabsf(lre[ch])), th = PI_HALF * lim[ch];
    float pr = rr * cosf(th), pi = rr * sinf(th);
#pragma unroll
    for (int s = 0; s < 3; ++s) { float nr = pr*pr - pi*pi, ni = 2.f*pr*pi; pr = nr; pi = ni; } // lambda^8
    float sr = 0.f, si = 0.f;
#pragma unroll 8
    for (int j = 0; j < CPS; ++j) {
        float2 e = E[((size_t)seg * CPS + j) * 4096 + chain];
        float nr = pr * sr - pi * si + e.x;
        float ni = pi * sr + pr * si + e.y;
        sr = nr; si = ni;
    }
    Esup[(size_t)seg * 4096 + chain] = make_float2(sr, si);
}

__global__ __launch_bounds__(256) void k_csup(
    const float* __restrict__ lre, const float* __restrict__ lim,
    const float2* __restrict__ x0p, const float2* __restrict__ Esup,
    float2* __restrict__ CarrySup)
{
    int chain = blockIdx.x * 256 + threadIdx.x;   // grid 16 -> 0..4095
    int ch = chain & 127;
    float rr = expf(-fabsf(lre[ch])), th = PI_HALF * lim[ch];
    float pr = rr * cosf(th), pi = rr * sinf(th);
#pragma unroll
    for (int s = 0; s < 8; ++s) { float nr = pr*pr - pi*pi, ni = 2.f*pr*pi; pr = nr; pi = ni; } // lambda^256
    float2 c0 = x0p[chain];
    float cr = c0.x, ci = c0.y;
#pragma unroll
    for (int s = 0; s < SEGN; ++s) {
        CarrySup[(size_t)s * 4096 + chain] = make_float2(cr, ci);
        float2 e = Esup[(size_t)s * 4096 + chain];
        float nr = pr * cr - pi * ci + e.x;
        float ni = pi * cr + pr * ci + e.y;
        cr = nr; ci = ni;
    }
}

__global__ __launch_bounds__(256) void k_cexp(
    const float* __restrict__ lre, const float* __restrict__ lim,
    const float2* __restrict__ E, const float2* __restrict__ CarrySup,
    float2* __restrict__ Carry)
{
    int g = blockIdx.x * 256 + threadIdx.x;
    int chain = g & 4095, seg = g >> 12, ch = chain & 127;
    float rr = expf(-fabsf(lre[ch])), th = PI_HALF * lim[ch];
    float pr = rr * cosf(th), pi = rr * sinf(th);
#pragma unroll
    for (int s = 0; s < 3; ++s) { float nr = pr*pr - pi*pi, ni = 2.f*pr*pi; pr = nr; pi = ni; } // lambda^8
    float2 cc = CarrySup[(size_t)seg * 4096 + chain];
    float cr = cc.x, ci = cc.y;
#pragma unroll 8
    for (int j = 0; j < CPS; ++j) {
        size_t idx = ((size_t)seg * CPS + j) * 4096 + chain;
        Carry[idx] = make_float2(cr, ci);
        float2 e = E[idx];
        float nr = pr * cr - pi * ci + e.x;
        float ni = pi * cr + pr * ci + e.y;
        cr = nr; ci = ni;
    }
}

// ---------------------------------------------------------------------------
// Pass 2: seeded scan + fused output GEMM. Per sub (2 steps):
//   stage sU(sub) || out-GEMM(sub-1)  -> barrier -> Bu MFMA + scan + dump sX
//   -> barrier.  sX columns interleaved (2j=re_j, 2j+1=im_j) matching Wp.
// ---------------------------------------------------------------------------
__global__ __launch_bounds__(256, 2) void k_pass2(
    const float* __restrict__ U, const unsigned short* __restrict__ Bp,
    const unsigned short* __restrict__ Wp,
    const float* __restrict__ lre, const float* __restrict__ lim,
    const float* __restrict__ bx2y,
    const float2* __restrict__ Carry, float* __restrict__ Y)
{
    __shared__ __align__(16) unsigned short sU[64 * 72];    // 9 KB
    __shared__ __align__(16) unsigned short sX[64 * 264];   // 33 KB

    const int tid = threadIdx.x, w = tid >> 6, lane = tid & 63;
    const int l31 = lane & 31, kh = lane >> 5;
    const int c = blockIdx.x;
    const int ch = w * 32 + l31;            // scan channel
    const int mtile = w & 1, ntile = w >> 1; // out-GEMM tile mapping

    float rr = expf(-fabsf(lre[ch])), th = PI_HALF * lim[ch];
    float lr = rr * cosf(th), li = rr * sinf(th);
    float ybias = bx2y[ntile * 32 + l31];

    bf16x8 bf[2][4];
#pragma unroll
    for (int nt = 0; nt < 2; ++nt)
#pragma unroll
        for (int kk = 0; kk < 4; ++kk)
            bf[nt][kk] = ldfrag(&Bp[(size_t)(nt * HH + ch) * NUU + kk * 16 + kh * 8]);

    // Seed from Carry
    float zr[16], zi[16];
#pragma unroll
    for (int r = 0; r < 16; ++r) {
        float2 v = Carry[(size_t)c * 4096 + crow(r, lane) * HH + ch];
        zr[r] = v.x; zi[r] = v.y;
    }

    for (int sub = 0; sub < 4; ++sub) {
        {   // stage U(sub) -> sU  (disjoint from sX)
            int row = tid >> 2, us = (tid & 3) * 16;
            int t = c * LCH + sub * 2 + (row >> 5), b = row & 31;
            const float4* s = (const float4*)(U + ((size_t)t * NBB + b) * NUU + us);
            float4 f0 = s[0], f1 = s[1], f2 = s[2], f3 = s[3];
            bf16x8 p0, p1;
            p0[0]=(__bf16)f0.x; p0[1]=(__bf16)f0.y; p0[2]=(__bf16)f0.z; p0[3]=(__bf16)f0.w;
            p0[4]=(__bf16)f1.x; p0[5]=(__bf16)f1.y; p0[6]=(__bf16)f1.z; p0[7]=(__bf16)f1.w;
            p1[0]=(__bf16)f2.x; p1[1]=(__bf16)f2.y; p1[2]=(__bf16)f2.z; p1[3]=(__bf16)f2.w;
            p1[4]=(__bf16)f3.x; p1[5]=(__bf16)f3.y; p1[6]=(__bf16)f3.z; p1[7]=(__bf16)f3.w;
            *(bf16x8*)&sU[row * 72 + us]     = p0;
            *(bf16x8*)&sU[row * 72 + us + 8] = p1;
        }

        if (sub > 0) {  // out-GEMM for sub-1 (reads sX written before last barrier)
            f32x16 ya;
#pragma unroll
            for (int r = 0; r < 16; ++r) ya[r] = 0.f;
#pragma unroll
            for (int kk = 0; kk < 16; ++kk) {
                bf16x8 xa = ldfrag(&sX[(mtile * 32 + l31) * 264 + kk * 16 + kh * 8]);
                bf16x8 wb = ldfrag(&Wp[(size_t)(ntile * 32 + l31) * NHH + kk * 16 + kh * 8]);
                ya = __builtin_amdgcn_mfma_f32_32x32x16_bf16(xa, wb, ya, 0, 0, 0);
            }
            int t = c * LCH + (sub - 1) * 2 + mtile;
#pragma unroll
            for (int r = 0; r < 16; ++r)
                Y[((size_t)t * NBB + crow(r, lane)) * NYY + ntile * 32 + l31] = ya[r] + ybias;
        }
        __syncthreads();

        // Bu MFMA
        f32x16 acc[2][2];
#pragma unroll
        for (int mt = 0; mt < 2; ++mt)
#pragma unroll
            for (int nt = 0; nt < 2; ++nt)
#pragma unroll
                for (int r = 0; r < 16; ++r) acc[mt][nt][r] = 0.f;

#pragma unroll
        for (int kk = 0; kk < 4; ++kk) {
            bf16x8 a0 = ldfrag(&sU[(l31)      * 72 + kk * 16 + kh * 8]);
            bf16x8 a1 = ldfrag(&sU[(32 + l31) * 72 + kk * 16 + kh * 8]);
            acc[0][0] = __builtin_amdgcn_mfma_f32_32x32x16_bf16(a0, bf[0][kk], acc[0][0], 0, 0, 0);
            acc[0][1] = __builtin_amdgcn_mfma_f32_32x32x16_bf16(a0, bf[1][kk], acc[0][1], 0, 0, 0);
            acc[1][0] = __builtin_amdgcn_mfma_f32_32x32x16_bf16(a1, bf[0][kk], acc[1][0], 0, 0, 0);
            acc[1][1] = __builtin_amdgcn_mfma_f32_32x32x16_bf16(a1, bf[1][kk], acc[1][1], 0, 0, 0);
        }

        // Scan + interleaved-pair dump (one b32 per (mt,r))
#pragma unroll
        for (int mt = 0; mt < 2; ++mt)
#pragma unroll
            for (int r = 0; r < 16; ++r) {
                float t0 = fmaf(lr, zr[r], acc[mt][0][r]); t0 = fmaf(-li, zi[r], t0);
                float t1 = fmaf(li, zr[r], acc[mt][1][r]); t1 = fmaf(lr, zi[r], t1);
                zr[r] = t0; zi[r] = t1;
                bf16x2 pv; pv[0] = (__bf16)t0; pv[1] = (__bf16)t1;
                *(bf16x2*)&sX[(mt * 32 + crow(r, lane)) * 264 + w * 64 + 2 * l31] = pv;
            }
        __syncthreads();
    }

    // Drain: out-GEMM for sub=3
    {
        f32x16 ya;
#pragma unroll
        for (int r = 0; r < 16; ++r) ya[r] = 0.f;
#pragma unroll
        for (int kk = 0; kk < 16; ++kk) {
            bf16x8 xa = ldfrag(&sX[(mtile * 32 + l31) * 264 + kk * 16 + kh * 8]);
            bf16x8 wb = ldfrag(&Wp[(size_t)(ntile * 32 + l31) * NHH + kk * 16 + kh * 8]);
            ya = __builtin_amdgcn_mfma_f32_32x32x16_bf16(xa, wb, ya, 0, 0, 0);
        }
        int t = c * LCH + 3 * 2 + mtile;
#pragma unroll
        for (int r = 0; r < 16; ++r)
            Y[((size_t)t * NBB + crow(r, lane)) * NYY + ntile * 32 + l31] = ya[r] + ybias;
    }
}

// ---------------------------------------------------------------------------
extern "C" void kernel_launch(void* const* d_in, const int* in_sizes, int n_in,
                              void* d_out, int out_size, void* d_ws, size_t ws_size,
                              hipStream_t stream) {
    const float* y0    = (const float*)d_in[0];
    const float* U     = (const float*)d_in[1];
    const float* lre   = (const float*)d_in[2];
    const float* lim   = (const float*)d_in[3];
    const float* B     = (const float*)d_in[4];
    const float* W_y2x = (const float*)d_in[5];
    const float* b_y2x = (const float*)d_in[6];
    const float* W_x2y = (const float*)d_in[7];
    const float* b_x2y = (const float*)d_in[8];
    float* Y = (float*)d_out;

    char* p = (char*)d_ws;
    float2* E        = (float2*)p; p += (size_t)CCH * 4096 * sizeof(float2);   // 16 MB
    float2* Carry    = (float2*)p; p += (size_t)CCH * 4096 * sizeof(float2);   // 16 MB
    float2* Esup     = (float2*)p; p += (size_t)SEGN * 4096 * sizeof(float2);  // 512 KB
    float2* CarrySup = (float2*)p; p += (size_t)SEGN * 4096 * sizeof(float2);  // 512 KB
    float2* x0p      = (float2*)p; p += (size_t)4096 * sizeof(float2);         // 32 KB
    unsigned short* Bp = (unsigned short*)p; p += 16384 * sizeof(unsigned short);
    unsigned short* Wp = (unsigned short*)p; p += 16384 * sizeof(unsigned short);

    k_prep <<<dim3(96),  dim3(256), 0, stream>>>(B, W_x2y, y0, W_y2x, b_y2x, Bp, Wp, x0p);
    k_pass1<<<dim3(CCH), dim3(256), 0, stream>>>(U, Bp, lre, lim, E);
    k_cseg <<<dim3(256), dim3(256), 0, stream>>>(lre, lim, E, Esup);
    k_csup <<<dim3(16),  dim3(256), 0, stream>>>(lre, lim, x0p, Esup, CarrySup);
    k_cexp <<<dim3(256), dim3(256), 0, stream>>>(lre, lim, E, CarrySup, Carry);
    k_pass2<<<dim3(CCH), dim3(256), 0, stream>>>(U, Bp, Wp, lre, lim, b_x2y, Carry, Y);
}